// Round 13
// baseline (72.424 us; speedup 1.0000x reference)
//
#include <hip/hip_runtime.h>

#define NP 140
#define NT 1024

typedef float2 f2;

__device__ __forceinline__ float sigmoid2pi(float x) {
    return 6.28318530717958647692f / (1.0f + __expf(-x));
}
__device__ __forceinline__ f2 cmulf(f2 a, f2 b) {
    return make_float2(a.x * b.x - a.y * b.y, a.x * b.y + a.y * b.x);
}
// ca*m + cb*o (complex)
__device__ __forceinline__ f2 comb(f2 ca, f2 m, f2 cb, f2 o) {
    return make_float2(ca.x * m.x - ca.y * m.y + cb.x * o.x - cb.y * o.y,
                       ca.x * m.y + ca.y * m.x + cb.x * o.y + cb.y * o.x);
}
// RX half: n = ch*m - i*sh*o
__device__ __forceinline__ f2 rxmix(float ch, float sh, f2 m, f2 o) {
    return make_float2(ch * m.x + sh * o.y, ch * m.y - sh * o.x);
}

// ---- lane exchange on the VALU pipe via DPP (measurement wires) ----
#define XOR1 0xB1   // quad_perm [1,0,3,2]
#define XOR2 0x4E   // quad_perm [2,3,0,1]
#define XOR8 0x128  // row_ror:8 (xor 8 within 16-lane row)
template<int CTRL>
__device__ __forceinline__ float xdpp(float v) {
    return __int_as_float(__builtin_amdgcn_update_dpp(0, __float_as_int(v), CTRL, 0xF, 0xF, true));
}
template<int CTRL>
__device__ __forceinline__ f2 xchg(f2 v) { return make_float2(xdpp<CTRL>(v.x), xdpp<CTRL>(v.y)); }
// xor4 exchange (DS pipe, one measurement wire only)
__device__ __forceinline__ f2 xchg4(f2 v) {
    return make_float2(
        __int_as_float(__builtin_amdgcn_ds_swizzle(__float_as_int(v.x), 0x101F)),
        __int_as_float(__builtin_amdgcn_ds_swizzle(__float_as_int(v.y), 0x101F)));
}

// ---- wave-64 reduction on the VALU via DPP; total lands in lane 63 ----
template<int CTRL>
__device__ __forceinline__ float dppadd(float v) {
    int t = __builtin_amdgcn_update_dpp(0, __float_as_int(v), CTRL, 0xF, 0xF, true);
    return v + __int_as_float(t);
}
__device__ __forceinline__ float wsum(float v) {
    v = dppadd<0x118>(v);   // row_shr:8
    v = dppadd<0x114>(v);   // row_shr:4
    v = dppadd<0x112>(v);   // row_shr:2
    v = dppadd<0x111>(v);   // row_shr:1
    v = dppadd<0x142>(v);   // row_bcast:15
    v = dppadd<0x143>(v);   // row_bcast:31 -> lane63 = total
    return v;
}

// LDS-only barrier (spill VMEM stays in flight)
#define BAR_LGKM { asm volatile("s_waitcnt lgkmcnt(0)" ::: "memory"); \
                   __builtin_amdgcn_s_barrier(); }

// 14-bit rotate-left and per-distance padded slot (compile-time)
// slotK(a) = a + (a>>4) + (a>>8) + K*(a>>12); K=4 for D=8 folds the lane bits
// that land in a[12:13] into the bank index (R12-verified). K=0 for D in
// {10,11,3,4} (R9-verified: those distances keep rt[12:13] off lane bits or
// at free 2-way aliasing).
constexpr unsigned rot14c(unsigned x, int d) {
    return ((x << d) | (x >> (14 - d))) & 16383u;
}
constexpr unsigned koffc(unsigned i, int d, int k) {
    unsigned c = rot14c(i, d);
    return (c + (c >> 4) + (c >> 8) + (unsigned)k * (c >> 12)) * 8u;
}

// ---------------- pair lists over the 4 local amp bits ----------------
#define P_B0(OP) OP(0,1) OP(2,3) OP(4,5) OP(6,7) OP(8,9) OP(10,11) OP(12,13) OP(14,15)
#define P_B1(OP) OP(0,2) OP(1,3) OP(4,6) OP(5,7) OP(8,10) OP(9,11) OP(12,14) OP(13,15)
#define P_B2(OP) OP(0,4) OP(1,5) OP(2,6) OP(3,7) OP(8,12) OP(9,13) OP(10,14) OP(11,15)
#define P_B3(OP) OP(0,8) OP(1,9) OP(2,10) OP(3,11) OP(4,12) OP(5,13) OP(6,14) OP(7,15)
#define P_32(OP) OP(8,12) OP(9,13) OP(10,14) OP(11,15)   // ctrl b3=1 -> tgt b2
#define P_21(OP) OP(4,6) OP(5,7) OP(12,14) OP(13,15)     // ctrl b2=1 -> tgt b1
#define P_10(OP) OP(2,3) OP(6,7) OP(10,11) OP(14,15)     // ctrl b1=1 -> tgt b0
#define P_23(OP) OP(4,12) OP(5,13) OP(6,14) OP(7,15)     // ctrl b2=1 -> tgt b3
#define P_12(OP) OP(2,6) OP(3,7) OP(10,14) OP(11,15)     // ctrl b1=1 -> tgt b2
#define P_01(OP) OP(1,3) OP(5,7) OP(9,11) OP(13,15)      // ctrl b0=1 -> tgt b1
#define ALL16(OP) OP(0) OP(1) OP(2) OP(3) OP(4) OP(5) OP(6) OP(7) OP(8) OP(9) OP(10) OP(11) OP(12) OP(13) OP(14) OP(15)

// ---------------- elementary gate ops on named registers ----------------
#define OP_RX(a_, b_) { f2 ta_ = st##a_; \
    st##a_ = rxmix(ch_, sh_, ta_, st##b_); st##b_ = rxmix(ch_, sh_, st##b_, ta_); }
#define OP_G1(a_, b_) { f2 ta_ = st##a_, tb_ = st##b_; \
    st##a_ = comb(u00_, ta_, u01_, tb_); st##b_ = comb(u10_, ta_, u11_, tb_); }
#define OP_MX(a_, b_) { \
    sx += st##a_.x * st##b_.x + st##a_.y * st##b_.y; \
    sy += st##a_.x * st##b_.y - st##a_.y * st##b_.x; \
    sz += st##a_.x * st##a_.x + st##a_.y * st##a_.y - st##b_.x * st##b_.x - st##b_.y * st##b_.y; }
#define OP_MD(i_) { f2 o_ = xchg<CT_>(st##i_); \
    sx += st##i_.x * o_.x + st##i_.y * o_.y; \
    sy += sg_ * (st##i_.x * o_.y - st##i_.y * o_.x); \
    sz += sg_ * (st##i_.x * st##i_.x + st##i_.y * st##i_.y); }
#define OP_MS(i_) { f2 o_ = xchg4(st##i_); \
    sx += st##i_.x * o_.x + st##i_.y * o_.y; \
    sy += sg_ * (st##i_.x * o_.y - st##i_.y * o_.x); \
    sz += sg_ * (st##i_.x * st##i_.x + st##i_.y * st##i_.y); }

// ---------------- gate macros ----------------
#define CRX_CL(CI_, PL) { f2 cs_ = csh2[CI_]; float ch_ = cs_.x, sh_ = cs_.y; PL(OP_RX) }
#define CRX_SEL0(CI_) { f2 cs_ = csh2[CI_]; float ch_ = cs_.x, sh_ = cs_.y; \
    if (tid & 1) { P_B3(OP_RX) } }
#define CRX_W512(CI_) { f2 cs_ = csh2[CI_]; float ch_ = cs_.x, sh_ = cs_.y; \
    if (tid & 512) { P_B0(OP_RX) } }
#define G1Q(q_, PL) { float4 ga_ = g1v[q_][0], gb_ = g1v[q_][1]; \
    f2 u00_ = make_float2(ga_.x, ga_.y), u01_ = make_float2(ga_.z, ga_.w); \
    f2 u10_ = make_float2(gb_.x, gb_.y), u11_ = make_float2(gb_.z, gb_.w); PL(OP_G1) }

// ---------------- measurement macros ----------------
#define RED_STORE(W_) { \
    sx = wsum(sx); sy = wsum(sy); sz = wsum(sz); \
    if ((tid & 63) == 63) { red[W_][tid >> 6][0] = sx; red[W_][tid >> 6][1] = sy; red[W_][tid >> 6][2] = sz; } }
#define MEAS(w_, PL) { float sx = 0.f, sy = 0.f, sz = 0.f; PL(OP_MX) \
    sx *= 2.f; sy *= 2.f; RED_STORE(w_) }
#define MEAS_D(w_, CTV_, SGM_) { constexpr int CT_ = CTV_; float sg_ = (tid & SGM_) ? -1.f : 1.f; \
    float sx = 0.f, sy = 0.f, sz = 0.f; ALL16(OP_MD) RED_STORE(w_) }
#define MEAS_SWZ(w_, SGM_) { float sg_ = (tid & SGM_) ? -1.f : 1.f; \
    float sx = 0.f, sy = 0.f, sz = 0.f; ALL16(OP_MS) RED_STORE(w_) }

// ---------------- layout transpose through LDS ----------------
// x_old = rotl14(x_new, D); slotK(a) = a + (a>>4) + (a>>8) + K*(a>>12).
// Write base: slotK(16*tid) = 17*tid + (tid>>4) + K*(tid>>8), offsets = +i.
// Read: addr = slotK(rt)*8 + koffc(i, D, K), rt = rotl14(tid<<4, D).
// Barriers are LDS-only (BAR_LGKM).
#define XPOSE(D_, K_) { \
    BAR_LGKM \
    { char* wb_ = (char*)exb + ((unsigned)(tid * 17 + (tid >> 4)) + (unsigned)(K_) * ((unsigned)tid >> 8)) * 8u; \
      *(f2*)(wb_ +   0) = st0;  *(f2*)(wb_ +   8) = st1;  *(f2*)(wb_ +  16) = st2;  *(f2*)(wb_ +  24) = st3; \
      *(f2*)(wb_ +  32) = st4;  *(f2*)(wb_ +  40) = st5;  *(f2*)(wb_ +  48) = st6;  *(f2*)(wb_ +  56) = st7; \
      *(f2*)(wb_ +  64) = st8;  *(f2*)(wb_ +  72) = st9;  *(f2*)(wb_ +  80) = st10; *(f2*)(wb_ +  88) = st11; \
      *(f2*)(wb_ +  96) = st12; *(f2*)(wb_ + 104) = st13; *(f2*)(wb_ + 112) = st14; *(f2*)(wb_ + 120) = st15; } \
    BAR_LGKM \
    { unsigned aw_ = (unsigned)tid << 4; \
      unsigned rt_ = ((aw_ << (D_)) | (aw_ >> (14 - (D_)))) & 16383u; \
      const char* rb_ = (const char*)exb + (rt_ + (rt_ >> 4) + (rt_ >> 8) + (unsigned)(K_) * (rt_ >> 12)) * 8u; \
      st0  = *(const f2*)(rb_ + koffc(0,  D_, K_)); st1  = *(const f2*)(rb_ + koffc(1,  D_, K_)); \
      st2  = *(const f2*)(rb_ + koffc(2,  D_, K_)); st3  = *(const f2*)(rb_ + koffc(3,  D_, K_)); \
      st4  = *(const f2*)(rb_ + koffc(4,  D_, K_)); st5  = *(const f2*)(rb_ + koffc(5,  D_, K_)); \
      st6  = *(const f2*)(rb_ + koffc(6,  D_, K_)); st7  = *(const f2*)(rb_ + koffc(7,  D_, K_)); \
      st8  = *(const f2*)(rb_ + koffc(8,  D_, K_)); st9  = *(const f2*)(rb_ + koffc(9,  D_, K_)); \
      st10 = *(const f2*)(rb_ + koffc(10, D_, K_)); st11 = *(const f2*)(rb_ + koffc(11, D_, K_)); \
      st12 = *(const f2*)(rb_ + koffc(12, D_, K_)); st13 = *(const f2*)(rb_ + koffc(13, D_, K_)); \
      st14 = *(const f2*)(rb_ + koffc(14, D_, K_)); st15 = *(const f2*)(rb_ + koffc(15, D_, K_)); } }

__global__
__attribute__((amdgpu_flat_work_group_size(1024, 1024), amdgpu_waves_per_eu(4, 4)))
void qfe_kernel(const float* __restrict__ params,
                const float* __restrict__ base,
                float* __restrict__ out)
{
    __shared__ f2 exb[17536];            // padded transpose buffer (max slot w/ K=4: 17481)
    __shared__ f2 v1c[14][2];            // layer-1 columns: u00, u10
    __shared__ float4 g1v[14][2];        // layer-2 fused 1q matrices (rows)
    __shared__ f2 csh2[56];              // CRX (cos, sin) half-angle, exec order
    __shared__ float red[14][16][3];     // per-wave measurement partials

    const int b = blockIdx.x;
    const int tid = threadIdx.x;

    // ------- precompute gate data (one-time, divergent) -------
    if (tid < 14) {                      // layer-1 1q columns acting on |0>
        int q = tid, a = 3 * q;
        float t1 = sigmoid2pi(params[b * NP + a] + base[a]);
        float t2 = sigmoid2pi(params[b * NP + a + 1] + base[a + 1]);
        float t3 = sigmoid2pi(params[b * NP + a + 2] + base[a + 2]);
        float s1, c1, s2, c2, s3, c3;
        __sincosf(0.5f * t1, &s1, &c1);
        __sincosf(0.5f * t2, &s2, &c2);
        __sincosf(0.5f * t3, &s3, &c3);
        f2 m00 = make_float2(c2 * c1, s2 * s1);
        f2 m10 = make_float2(s2 * c1, -c2 * s1);
        f2 em = make_float2(c3, -s3), ep = make_float2(c3, s3);
        v1c[q][0] = cmulf(em, m00);
        v1c[q][1] = cmulf(ep, m10);
    } else if (tid >= 64 && tid < 78) {  // layer-2 fused U = Rz*Ry*Rx
        int q = tid - 64, a = 70 + 3 * q;
        float t1 = sigmoid2pi(params[b * NP + a] + base[a]);
        float t2 = sigmoid2pi(params[b * NP + a + 1] + base[a + 1]);
        float t3 = sigmoid2pi(params[b * NP + a + 2] + base[a + 2]);
        float s1, c1, s2, c2, s3, c3;
        __sincosf(0.5f * t1, &s1, &c1);
        __sincosf(0.5f * t2, &s2, &c2);
        __sincosf(0.5f * t3, &s3, &c3);
        f2 m00 = make_float2(c2 * c1, s2 * s1);
        f2 m01 = make_float2(-s2 * c1, -c2 * s1);
        f2 m10 = make_float2(s2 * c1, -c2 * s1);
        f2 m11 = make_float2(c2 * c1, -s2 * s1);
        f2 em = make_float2(c3, -s3), ep = make_float2(c3, s3);
        f2 u00 = cmulf(em, m00), u01 = cmulf(em, m01);
        f2 u10 = cmulf(ep, m10), u11 = cmulf(ep, m11);
        g1v[q][0] = make_float4(u00.x, u00.y, u01.x, u01.y);
        g1v[q][1] = make_float4(u10.x, u10.y, u11.x, u11.y);
    } else if (tid >= 128 && tid < 184) { // CRX cos/sin, execution order
        int s = tid - 128;
        int layer = s / 28, k = s % 28;
        int aidx = layer * 70 + (k < 14 ? 42 + k : 56 + (k - 14));
        float th = sigmoid2pi(params[b * NP + aidx] + base[aidx]);
        float sh, ch;
        __sincosf(0.5f * th, &sh, &ch);
        csh2[s] = make_float2(ch, sh);
    }
    __syncthreads();

    // ------- initial state (layer-1 1q product) in layout r=5 -------
    // tid bit j -> qubit: 0:q0 1:q13 2:q12 3:q11 4:q10 5:q9 6:q8 7:q7 8:q6 9:q5
    // local bits: b3=q1 b2=q2 b1=q3 b0=q4
    f2 F = v1c[0][tid & 1];
    F = cmulf(F, v1c[13][(tid >> 1) & 1]);
    F = cmulf(F, v1c[12][(tid >> 2) & 1]);
    F = cmulf(F, v1c[11][(tid >> 3) & 1]);
    F = cmulf(F, v1c[10][(tid >> 4) & 1]);
    F = cmulf(F, v1c[9][(tid >> 5) & 1]);
    F = cmulf(F, v1c[8][(tid >> 6) & 1]);
    F = cmulf(F, v1c[7][(tid >> 7) & 1]);
    F = cmulf(F, v1c[6][(tid >> 8) & 1]);
    F = cmulf(F, v1c[5][(tid >> 9) & 1]);

    f2 st0, st1, st2, st3, st4, st5, st6, st7, st8, st9, st10, st11, st12, st13, st14, st15;
    st0 = cmulf(F, v1c[1][0]);  st8 = cmulf(F, v1c[1][1]);                  // b3 = q1
    st4 = cmulf(st0, v1c[2][1]); st12 = cmulf(st8, v1c[2][1]);              // b2 = q2
    st0 = cmulf(st0, v1c[2][0]); st8  = cmulf(st8, v1c[2][0]);
    st2  = cmulf(st0, v1c[3][1]); st6  = cmulf(st4,  v1c[3][1]);            // b1 = q3
    st10 = cmulf(st8, v1c[3][1]); st14 = cmulf(st12, v1c[3][1]);
    st0  = cmulf(st0, v1c[3][0]); st4  = cmulf(st4,  v1c[3][0]);
    st8  = cmulf(st8, v1c[3][0]); st12 = cmulf(st12, v1c[3][0]);
    st1  = cmulf(st0,  v1c[4][1]); st3  = cmulf(st2,  v1c[4][1]);           // b0 = q4
    st5  = cmulf(st4,  v1c[4][1]); st7  = cmulf(st6,  v1c[4][1]);
    st9  = cmulf(st8,  v1c[4][1]); st11 = cmulf(st10, v1c[4][1]);
    st13 = cmulf(st12, v1c[4][1]); st15 = cmulf(st14, v1c[4][1]);
    st0  = cmulf(st0,  v1c[4][0]); st2  = cmulf(st2,  v1c[4][0]);
    st4  = cmulf(st4,  v1c[4][0]); st6  = cmulf(st6,  v1c[4][0]);
    st8  = cmulf(st8,  v1c[4][0]); st10 = cmulf(st10, v1c[4][0]);
    st12 = cmulf(st12, v1c[4][0]); st14 = cmulf(st14, v1c[4][0]);

    // ================= LAYER 1 (R9/R11-proven schedule) =================
    CRX_SEL0(0) CRX_CL(1, P_32) CRX_CL(2, P_21) CRX_CL(3, P_10)
    XPOSE(10, 0)   // r 5->9
    CRX_SEL0(4) CRX_CL(5, P_32) CRX_CL(6, P_21) CRX_CL(7, P_10)
    XPOSE(10, 0)   // 9->13
    CRX_SEL0(8) CRX_CL(9, P_32) CRX_CL(10, P_21) CRX_CL(11, P_10)
    XPOSE(11, 0)   // 13->2
    CRX_CL(12, P_32) CRX_CL(13, P_21) CRX_CL(14, P_23)
    XPOSE(3, 0)    // 2->13
    CRX_CL(15, P_01) CRX_CL(16, P_12) CRX_CL(17, P_23)
    XPOSE(4, 0)    // 13->9
    CRX_W512(18) CRX_CL(19, P_01) CRX_CL(20, P_12) CRX_CL(21, P_23)
    XPOSE(4, 0)    // 9->5
    CRX_W512(22) CRX_CL(23, P_01) CRX_CL(24, P_12) CRX_CL(25, P_23)
    XPOSE(4, 0)    // 5->1
    CRX_W512(26) CRX_CL(27, P_01)

    // ================= LAYER 2 =================
    // r=1 locals: b0=q0 b1=q13 b2=q12 b3=q11
    G1Q(0, P_B0) G1Q(13, P_B1) G1Q(12, P_B2) G1Q(11, P_B3)
    XPOSE(10, 0)   // 1->5
    G1Q(1, P_B3) G1Q(2, P_B2) G1Q(3, P_B1) G1Q(4, P_B0)
    CRX_SEL0(28) CRX_CL(29, P_32) CRX_CL(30, P_21) CRX_CL(31, P_10)
    XPOSE(10, 0)   // 5->9
    G1Q(5, P_B3) G1Q(6, P_B2) G1Q(7, P_B1) G1Q(8, P_B0)
    CRX_SEL0(32) CRX_CL(33, P_32) CRX_CL(34, P_21) CRX_CL(35, P_10)
    XPOSE(10, 0)   // 9->13
    G1Q(9, P_B3) G1Q(10, P_B2)
    CRX_SEL0(36) CRX_CL(37, P_32) CRX_CL(38, P_21) CRX_CL(39, P_10)
    XPOSE(11, 0)   // 13->2
    CRX_CL(40, P_32) CRX_CL(41, P_21) CRX_CL(42, P_23)
    XPOSE(3, 0)    // 2->13
    CRX_CL(43, P_01) CRX_CL(44, P_12) CRX_CL(45, P_23)
    XPOSE(4, 0)    // 13->9
    CRX_W512(46) CRX_CL(47, P_01) CRX_CL(48, P_12) CRX_CL(49, P_23)
    XPOSE(4, 0)    // 9->5
    CRX_W512(50) CRX_CL(51, P_01) CRX_CL(52, P_12) CRX_CL(53, P_23)
    XPOSE(4, 0)    // 5->1
    CRX_W512(54) CRX_CL(55, P_01)

    // ================= MEASUREMENTS (1 XPOSE instead of 3) =================
    // r=1: q0@b0 q13@b1 q12@b2 q11@b3; q10@tid0 q9@tid1 q8@tid2 q7@tid3
    MEAS(0, P_B0) MEAS(13, P_B1) MEAS(12, P_B2) MEAS(11, P_B3)
    MEAS_D(10, XOR1, 1) MEAS_D(9, XOR2, 2)
    MEAS_SWZ(8, 4) MEAS_D(7, XOR8, 8)
    XPOSE(8, 4)    // r 1->7: q6@b0 q5@b1 q4@b2 q3@b3 q2@tid0 q1@tid1
    MEAS(6, P_B0) MEAS(5, P_B1) MEAS(4, P_B2) MEAS(3, P_B3)
    MEAS_D(2, XOR1, 1) MEAS_D(1, XOR2, 2)

    __syncthreads();
    if (tid < 42) {
        int comp = tid / 14, w = tid % 14;
        float s = 0.f;
        #pragma unroll
        for (int k = 0; k < 16; ++k) s += red[w][k][comp];
        out[b * 42 + comp * 14 + w] = s;
    }
}

extern "C" void kernel_launch(void* const* d_in, const int* in_sizes, int n_in,
                              void* d_out, int out_size, void* d_ws, size_t ws_size,
                              hipStream_t stream) {
    const float* params = (const float*)d_in[0];   // [B, 140]
    const float* base   = (const float*)d_in[1];   // [140]
    float* out = (float*)d_out;                    // [B, 42]
    const int B = in_sizes[0] / NP;
    qfe_kernel<<<B, NT, 0, stream>>>(params, base, out);
}

// Round 14
// 68.691 us; speedup vs baseline: 1.0544x; 1.0544x over previous
//
#include <hip/hip_runtime.h>

#define NP 140
#define NT 1024

typedef float2 f2;

__device__ __forceinline__ float sigmoid2pi(float x) {
    return 6.28318530717958647692f / (1.0f + __expf(-x));
}
__device__ __forceinline__ f2 cmulf(f2 a, f2 b) {
    return make_float2(a.x * b.x - a.y * b.y, a.x * b.y + a.y * b.x);
}
// ca*m + cb*o (complex)
__device__ __forceinline__ f2 comb(f2 ca, f2 m, f2 cb, f2 o) {
    return make_float2(ca.x * m.x - ca.y * m.y + cb.x * o.x - cb.y * o.y,
                       ca.x * m.y + ca.y * m.x + cb.x * o.y + cb.y * o.x);
}
// RX half: n = ch*m - i*sh*o
__device__ __forceinline__ f2 rxmix(float ch, float sh, f2 m, f2 o) {
    return make_float2(ch * m.x + sh * o.y, ch * m.y - sh * o.x);
}

// ---- wave-64 reduction on the VALU via DPP (no DS ops); total lands in lane 63 ----
template<int CTRL>
__device__ __forceinline__ float dppadd(float v) {
    int t = __builtin_amdgcn_update_dpp(0, __float_as_int(v), CTRL, 0xF, 0xF, true);
    return v + __int_as_float(t);
}
__device__ __forceinline__ float wsum(float v) {
    v = dppadd<0x118>(v);   // row_shr:8
    v = dppadd<0x114>(v);   // row_shr:4
    v = dppadd<0x112>(v);   // row_shr:2
    v = dppadd<0x111>(v);   // row_shr:1
    v = dppadd<0x142>(v);   // row_bcast:15
    v = dppadd<0x143>(v);   // row_bcast:31 -> lane63 = total
    return v;
}

// LDS-only barrier: wait DS ops, then raw s_barrier — does NOT drain the
// scratch-spill VMEM queue the way __syncthreads() (vmcnt(0)) does.
#define BAR_LGKM { asm volatile("s_waitcnt lgkmcnt(0)" ::: "memory"); \
                   __builtin_amdgcn_s_barrier(); }

// 14-bit rotate-left and padded-slot, compile-time for constants
constexpr unsigned rot14c(unsigned x, int d) {
    return ((x << d) | (x >> (14 - d))) & 16383u;
}
constexpr unsigned koffc(unsigned i, int d) {
    unsigned c = rot14c(i, d);
    return (c + (c >> 4) + (c >> 8)) * 8u;   // byte offset of padded slot
}

// ---------------- pair lists over the 4 local amp bits ----------------
#define P_B0(OP) OP(0,1) OP(2,3) OP(4,5) OP(6,7) OP(8,9) OP(10,11) OP(12,13) OP(14,15)
#define P_B1(OP) OP(0,2) OP(1,3) OP(4,6) OP(5,7) OP(8,10) OP(9,11) OP(12,14) OP(13,15)
#define P_B2(OP) OP(0,4) OP(1,5) OP(2,6) OP(3,7) OP(8,12) OP(9,13) OP(10,14) OP(11,15)
#define P_B3(OP) OP(0,8) OP(1,9) OP(2,10) OP(3,11) OP(4,12) OP(5,13) OP(6,14) OP(7,15)
#define P_32(OP) OP(8,12) OP(9,13) OP(10,14) OP(11,15)   // ctrl b3=1 -> tgt b2
#define P_21(OP) OP(4,6) OP(5,7) OP(12,14) OP(13,15)     // ctrl b2=1 -> tgt b1
#define P_10(OP) OP(2,3) OP(6,7) OP(10,11) OP(14,15)     // ctrl b1=1 -> tgt b0
#define P_23(OP) OP(4,12) OP(5,13) OP(6,14) OP(7,15)     // ctrl b2=1 -> tgt b3
#define P_12(OP) OP(2,6) OP(3,7) OP(10,14) OP(11,15)     // ctrl b1=1 -> tgt b2
#define P_01(OP) OP(1,3) OP(5,7) OP(9,11) OP(13,15)      // ctrl b0=1 -> tgt b1

// ---------------- elementary gate ops on named registers ----------------
#define OP_RX(a_, b_) { f2 ta_ = st##a_; \
    st##a_ = rxmix(ch_, sh_, ta_, st##b_); st##b_ = rxmix(ch_, sh_, st##b_, ta_); }
#define OP_G1(a_, b_) { f2 ta_ = st##a_, tb_ = st##b_; \
    st##a_ = comb(u00_, ta_, u01_, tb_); st##b_ = comb(u10_, ta_, u11_, tb_); }
#define OP_MX(a_, b_) { \
    sx += st##a_.x * st##b_.x + st##a_.y * st##b_.y; \
    sy += st##a_.x * st##b_.y - st##a_.y * st##b_.x; \
    sz += st##a_.x * st##a_.x + st##a_.y * st##a_.y - st##b_.x * st##b_.x - st##b_.y * st##b_.y; }

// ---------------- gate macros ----------------
#define CRX_CL(CI_, PL) { f2 cs_ = csh2[CI_]; float ch_ = cs_.x, sh_ = cs_.y; PL(OP_RX) }
#define CRX_SEL0(CI_) { f2 cs_ = csh2[CI_]; float ch_ = cs_.x, sh_ = cs_.y; \
    if (tid & 1) { P_B3(OP_RX) } }
#define CRX_W512(CI_) { f2 cs_ = csh2[CI_]; float ch_ = cs_.x, sh_ = cs_.y; \
    if (tid & 512) { P_B0(OP_RX) } }
#define G1Q(q_, PL) { float4 ga_ = g1v[q_][0], gb_ = g1v[q_][1]; \
    f2 u00_ = make_float2(ga_.x, ga_.y), u01_ = make_float2(ga_.z, ga_.w); \
    f2 u10_ = make_float2(gb_.x, gb_.y), u11_ = make_float2(gb_.z, gb_.w); PL(OP_G1) }
#define MEAS(w_, PL) { float sx = 0.f, sy = 0.f, sz = 0.f; PL(OP_MX) \
    sx = wsum(2.f * sx); sy = wsum(2.f * sy); sz = wsum(sz); \
    if ((tid & 63) == 63) { red[w_][tid >> 6][0] = sx; red[w_][tid >> 6][1] = sy; red[w_][tid >> 6][2] = sz; } }

// ---------------- layout transpose through LDS ----------------
// x_old = rotl14(x_new, D); padded slot = a + (a>>4) + (a>>8).
// Write base: slot(16*tid + i) = 17*tid + (tid>>4) + i  (i = imm offset).
// Read: addr = padslot(Rt)*8 + koffc(i,D), Rt = rotl14(tid<<4, D) (disjoint bits).
// Barriers are LDS-only (BAR_LGKM): scratch-spill VMEM traffic stays in flight.
#define XPOSE(D_) { \
    BAR_LGKM \
    { char* wb_ = (char*)exb + (unsigned)(tid * 17 + (tid >> 4)) * 8u; \
      *(f2*)(wb_ +   0) = st0;  *(f2*)(wb_ +   8) = st1;  *(f2*)(wb_ +  16) = st2;  *(f2*)(wb_ +  24) = st3; \
      *(f2*)(wb_ +  32) = st4;  *(f2*)(wb_ +  40) = st5;  *(f2*)(wb_ +  48) = st6;  *(f2*)(wb_ +  56) = st7; \
      *(f2*)(wb_ +  64) = st8;  *(f2*)(wb_ +  72) = st9;  *(f2*)(wb_ +  80) = st10; *(f2*)(wb_ +  88) = st11; \
      *(f2*)(wb_ +  96) = st12; *(f2*)(wb_ + 104) = st13; *(f2*)(wb_ + 112) = st14; *(f2*)(wb_ + 120) = st15; } \
    BAR_LGKM \
    { unsigned aw_ = (unsigned)tid << 4; \
      unsigned rt_ = ((aw_ << (D_)) | (aw_ >> (14 - (D_)))) & 16383u; \
      const char* rb_ = (const char*)exb + (rt_ + (rt_ >> 4) + (rt_ >> 8)) * 8u; \
      st0  = *(const f2*)(rb_ + koffc(0,  D_)); st1  = *(const f2*)(rb_ + koffc(1,  D_)); \
      st2  = *(const f2*)(rb_ + koffc(2,  D_)); st3  = *(const f2*)(rb_ + koffc(3,  D_)); \
      st4  = *(const f2*)(rb_ + koffc(4,  D_)); st5  = *(const f2*)(rb_ + koffc(5,  D_)); \
      st6  = *(const f2*)(rb_ + koffc(6,  D_)); st7  = *(const f2*)(rb_ + koffc(7,  D_)); \
      st8  = *(const f2*)(rb_ + koffc(8,  D_)); st9  = *(const f2*)(rb_ + koffc(9,  D_)); \
      st10 = *(const f2*)(rb_ + koffc(10, D_)); st11 = *(const f2*)(rb_ + koffc(11, D_)); \
      st12 = *(const f2*)(rb_ + koffc(12, D_)); st13 = *(const f2*)(rb_ + koffc(13, D_)); \
      st14 = *(const f2*)(rb_ + koffc(14, D_)); st15 = *(const f2*)(rb_ + koffc(15, D_)); } }

__global__
__attribute__((amdgpu_flat_work_group_size(1024, 1024), amdgpu_waves_per_eu(4, 4)))
void qfe_kernel(const float* __restrict__ params,
                const float* __restrict__ base,
                float* __restrict__ out)
{
    __shared__ f2 exb[17472];            // 139.8 KB padded transpose buffer
    __shared__ f2 v1c[14][2];            // layer-1 columns: u00, u10
    __shared__ float4 g1v[14][2];        // layer-2 fused 1q matrices (rows)
    __shared__ f2 csh2[56];              // CRX (cos, sin) half-angle, exec order
    __shared__ float red[14][16][3];     // per-wave measurement partials

    const int b = blockIdx.x;
    const int tid = threadIdx.x;

    // ------- precompute gate data (one-time, divergent) -------
    if (tid < 14) {                      // layer-1 1q columns acting on |0>
        int q = tid, a = 3 * q;
        float t1 = sigmoid2pi(params[b * NP + a] + base[a]);
        float t2 = sigmoid2pi(params[b * NP + a + 1] + base[a + 1]);
        float t3 = sigmoid2pi(params[b * NP + a + 2] + base[a + 2]);
        float s1, c1, s2, c2, s3, c3;
        __sincosf(0.5f * t1, &s1, &c1);
        __sincosf(0.5f * t2, &s2, &c2);
        __sincosf(0.5f * t3, &s3, &c3);
        f2 m00 = make_float2(c2 * c1, s2 * s1);
        f2 m10 = make_float2(s2 * c1, -c2 * s1);
        f2 em = make_float2(c3, -s3), ep = make_float2(c3, s3);
        v1c[q][0] = cmulf(em, m00);
        v1c[q][1] = cmulf(ep, m10);
    } else if (tid >= 64 && tid < 78) {  // layer-2 fused U = Rz*Ry*Rx
        int q = tid - 64, a = 70 + 3 * q;
        float t1 = sigmoid2pi(params[b * NP + a] + base[a]);
        float t2 = sigmoid2pi(params[b * NP + a + 1] + base[a + 1]);
        float t3 = sigmoid2pi(params[b * NP + a + 2] + base[a + 2]);
        float s1, c1, s2, c2, s3, c3;
        __sincosf(0.5f * t1, &s1, &c1);
        __sincosf(0.5f * t2, &s2, &c2);
        __sincosf(0.5f * t3, &s3, &c3);
        f2 m00 = make_float2(c2 * c1, s2 * s1);
        f2 m01 = make_float2(-s2 * c1, -c2 * s1);
        f2 m10 = make_float2(s2 * c1, -c2 * s1);
        f2 m11 = make_float2(c2 * c1, -s2 * s1);
        f2 em = make_float2(c3, -s3), ep = make_float2(c3, s3);
        f2 u00 = cmulf(em, m00), u01 = cmulf(em, m01);
        f2 u10 = cmulf(ep, m10), u11 = cmulf(ep, m11);
        g1v[q][0] = make_float4(u00.x, u00.y, u01.x, u01.y);
        g1v[q][1] = make_float4(u10.x, u10.y, u11.x, u11.y);
    } else if (tid >= 128 && tid < 184) { // CRX cos/sin, execution order
        int s = tid - 128;
        int layer = s / 28, k = s % 28;
        int aidx = layer * 70 + (k < 14 ? 42 + k : 56 + (k - 14));
        float th = sigmoid2pi(params[b * NP + aidx] + base[aidx]);
        float sh, ch;
        __sincosf(0.5f * th, &sh, &ch);
        csh2[s] = make_float2(ch, sh);
    }
    __syncthreads();

    // ------- initial state (layer-1 1q product) in layout r=5 -------
    // tid bit j -> qubit: 0:q0 1:q13 2:q12 3:q11 4:q10 5:q9 6:q8 7:q7 8:q6 9:q5
    // local bits: b3=q1 b2=q2 b1=q3 b0=q4
    f2 F = v1c[0][tid & 1];
    F = cmulf(F, v1c[13][(tid >> 1) & 1]);
    F = cmulf(F, v1c[12][(tid >> 2) & 1]);
    F = cmulf(F, v1c[11][(tid >> 3) & 1]);
    F = cmulf(F, v1c[10][(tid >> 4) & 1]);
    F = cmulf(F, v1c[9][(tid >> 5) & 1]);
    F = cmulf(F, v1c[8][(tid >> 6) & 1]);
    F = cmulf(F, v1c[7][(tid >> 7) & 1]);
    F = cmulf(F, v1c[6][(tid >> 8) & 1]);
    F = cmulf(F, v1c[5][(tid >> 9) & 1]);

    f2 st0, st1, st2, st3, st4, st5, st6, st7, st8, st9, st10, st11, st12, st13, st14, st15;
    st0 = cmulf(F, v1c[1][0]);  st8 = cmulf(F, v1c[1][1]);                  // b3 = q1
    st4 = cmulf(st0, v1c[2][1]); st12 = cmulf(st8, v1c[2][1]);              // b2 = q2
    st0 = cmulf(st0, v1c[2][0]); st8  = cmulf(st8, v1c[2][0]);
    st2  = cmulf(st0, v1c[3][1]); st6  = cmulf(st4,  v1c[3][1]);            // b1 = q3
    st10 = cmulf(st8, v1c[3][1]); st14 = cmulf(st12, v1c[3][1]);
    st0  = cmulf(st0, v1c[3][0]); st4  = cmulf(st4,  v1c[3][0]);
    st8  = cmulf(st8, v1c[3][0]); st12 = cmulf(st12, v1c[3][0]);
    st1  = cmulf(st0,  v1c[4][1]); st3  = cmulf(st2,  v1c[4][1]);           // b0 = q4
    st5  = cmulf(st4,  v1c[4][1]); st7  = cmulf(st6,  v1c[4][1]);
    st9  = cmulf(st8,  v1c[4][1]); st11 = cmulf(st10, v1c[4][1]);
    st13 = cmulf(st12, v1c[4][1]); st15 = cmulf(st14, v1c[4][1]);
    st0  = cmulf(st0,  v1c[4][0]); st2  = cmulf(st2,  v1c[4][0]);
    st4  = cmulf(st4,  v1c[4][0]); st6  = cmulf(st6,  v1c[4][0]);
    st8  = cmulf(st8,  v1c[4][0]); st10 = cmulf(st10, v1c[4][0]);
    st12 = cmulf(st12, v1c[4][0]); st14 = cmulf(st14, v1c[4][0]);

    // ================= LAYER 1 =================
    // r=5: fwd c=0..3
    CRX_SEL0(0) CRX_CL(1, P_32) CRX_CL(2, P_21) CRX_CL(3, P_10)
    XPOSE(10)   // r 5->9
    CRX_SEL0(4) CRX_CL(5, P_32) CRX_CL(6, P_21) CRX_CL(7, P_10)
    XPOSE(10)   // 9->13
    CRX_SEL0(8) CRX_CL(9, P_32) CRX_CL(10, P_21) CRX_CL(11, P_10)
    XPOSE(11)   // 13->2
    CRX_CL(12, P_32) CRX_CL(13, P_21) CRX_CL(14, P_23)
    XPOSE(3)    // 2->13
    CRX_CL(15, P_01) CRX_CL(16, P_12) CRX_CL(17, P_23)
    XPOSE(4)    // 13->9
    CRX_W512(18) CRX_CL(19, P_01) CRX_CL(20, P_12) CRX_CL(21, P_23)
    XPOSE(4)    // 9->5
    CRX_W512(22) CRX_CL(23, P_01) CRX_CL(24, P_12) CRX_CL(25, P_23)
    XPOSE(4)    // 5->1
    CRX_W512(26) CRX_CL(27, P_01)

    // ================= LAYER 2 =================
    // r=1 locals: b0=q0 b1=q13 b2=q12 b3=q11
    G1Q(0, P_B0) G1Q(13, P_B1) G1Q(12, P_B2) G1Q(11, P_B3)
    XPOSE(10)   // 1->5
    G1Q(1, P_B3) G1Q(2, P_B2) G1Q(3, P_B1) G1Q(4, P_B0)
    CRX_SEL0(28) CRX_CL(29, P_32) CRX_CL(30, P_21) CRX_CL(31, P_10)
    XPOSE(10)   // 5->9
    G1Q(5, P_B3) G1Q(6, P_B2) G1Q(7, P_B1) G1Q(8, P_B0)
    CRX_SEL0(32) CRX_CL(33, P_32) CRX_CL(34, P_21) CRX_CL(35, P_10)
    XPOSE(10)   // 9->13
    G1Q(9, P_B3) G1Q(10, P_B2)
    CRX_SEL0(36) CRX_CL(37, P_32) CRX_CL(38, P_21) CRX_CL(39, P_10)
    XPOSE(11)   // 13->2
    CRX_CL(40, P_32) CRX_CL(41, P_21) CRX_CL(42, P_23)
    XPOSE(3)    // 2->13
    CRX_CL(43, P_01) CRX_CL(44, P_12) CRX_CL(45, P_23)
    XPOSE(4)    // 13->9
    CRX_W512(46) CRX_CL(47, P_01) CRX_CL(48, P_12) CRX_CL(49, P_23)
    XPOSE(4)    // 9->5
    CRX_W512(50) CRX_CL(51, P_01) CRX_CL(52, P_12) CRX_CL(53, P_23)
    XPOSE(4)    // 5->1
    CRX_W512(54) CRX_CL(55, P_01)

    // ================= MEASUREMENTS (all wires local) =================
    MEAS(0, P_B0) MEAS(13, P_B1) MEAS(12, P_B2) MEAS(11, P_B3)
    XPOSE(10)   // 1->5
    MEAS(1, P_B3) MEAS(2, P_B2) MEAS(3, P_B1) MEAS(4, P_B0)
    XPOSE(10)   // 5->9
    MEAS(5, P_B3) MEAS(6, P_B2) MEAS(7, P_B1) MEAS(8, P_B0)
    XPOSE(10)   // 9->13
    MEAS(9, P_B3) MEAS(10, P_B2)

    __syncthreads();
    if (tid < 42) {
        int comp = tid / 14, w = tid % 14;
        float s = 0.f;
        #pragma unroll
        for (int k = 0; k < 16; ++k) s += red[w][k][comp];
        out[b * 42 + comp * 14 + w] = s;
    }
}

extern "C" void kernel_launch(void* const* d_in, const int* in_sizes, int n_in,
                              void* d_out, int out_size, void* d_ws, size_t ws_size,
                              hipStream_t stream) {
    const float* params = (const float*)d_in[0];   // [B, 140]
    const float* base   = (const float*)d_in[1];   // [140]
    float* out = (float*)d_out;                    // [B, 42]
    const int B = in_sizes[0] / NP;
    qfe_kernel<<<B, NT, 0, stream>>>(params, base, out);
}